// Round 2
// baseline (253.692 us; speedup 1.0000x reference)
//
#include <hip/hip_runtime.h>

typedef unsigned short ushort_t;
typedef unsigned int uint_t;

typedef __bf16 bf16x8 __attribute__((ext_vector_type(8)));
typedef float f32x4 __attribute__((ext_vector_type(4)));

#define N_NODES 50000
#define N_EDGES 800000
#define DIM 128
#define NUM_GRAPHS 512
#define LDA 136  // padded LDS row stride in bf16 elems (128+8)

// ELL adjacency: fixed 64 slots per node (in-degree ~Poisson(16), max ~35;
// P(deg>64) astronomically small. Guarded anyway: overflow slots dropped.)
#define ELL_CAP 64

// XCD-bucketed edge scatter: 8 dst-range groups, group = blockIdx&7 so each
// group's cnt/ell region (25KB + 1.6MB) stays in ONE XCD's L2 (round-robin
// block->XCD dispatch). Kills atomic line ping-pong + write amplification.
#define EDGE_GROUPS 8
#define EDGE_BUCKET ((N_NODES + EDGE_GROUPS - 1) / EDGE_GROUPS)  // 6250
#define EDGE_CHUNK 2048
#define EDGE_CHUNKS ((N_EDGES + EDGE_CHUNK - 1) / EDGE_CHUNK)    // 391
#define EDGE_BLOCKS (EDGE_CHUNKS * EDGE_GROUPS)                  // 3128

// prep_all block ranges (edge blocks first: they are the critical path)
#define PREP_X_BLOCKS 6250                    // conv_x: only does work when f32 input
#define PREP_W_BLOCKS 256                     // wperm: 65536 / 256
#define PREP_B_BLOCKS 196                     // batch: 50000 / 256
#define PREP_TOTAL (EDGE_BLOCKS + PREP_X_BLOCKS + PREP_W_BLOCKS + PREP_B_BLOCKS + 1)

__device__ __forceinline__ float bf2f(ushort_t u) {
    return __uint_as_float(((uint_t)u) << 16);
}
__device__ __forceinline__ ushort_t f2bf(float f) {
    uint_t u = __float_as_uint(f);
    u = (u + 0x7FFF + ((u >> 16) & 1)) >> 16;  // RNE
    return (ushort_t)u;
}
__device__ __forceinline__ bf16x8 as_bf16x8(uint4 v) {
    return __builtin_bit_cast(bf16x8, v);
}

// ---------------- zero (degree + gsum) + dtype detection (merged) ----------------
__global__ void zero_detect_kernel(int* cnt, float* gsum, const void* xraw,
                                   const void* eiraw, int* flags) {
    int i = blockIdx.x * 256 + threadIdx.x;
    if (i < N_NODES) cnt[i] = 0;
    if (i < NUM_GRAPHS * DIM) gsum[i] = 0.f;
    if (i == 0) {
        const ushort_t* u = (const ushort_t*)xraw;
        int extreme = 0;
        for (int k = 0; k < 128; ++k) {
            int e = (u[k] >> 7) & 0xFF;
            if (e >= 0xC0) extreme++;  // |x| >= 2^65: impossible for bf16 N(0,1)
        }
        flags[0] = (extreme > 8) ? 1 : 0;
        const int* p = (const int*)eiraw;
        int nonzero = 0;
        for (int k = 1; k < 64; k += 2) nonzero += (p[k] != 0);
        flags[1] = (nonzero == 0) ? 1 : 0;  // all high-halves zero => int64
    }
}

// ---------------- merged canonicalization + XCD-bucketed ELL build ----------------
__global__ __launch_bounds__(256) void prep_all_kernel(
    const void* xraw, const void* braw, const void* eiraw,
    const void* W0, const void* W1, const void* W2, const void* W3,
    const void* pb1a, const void* pb1b, const void* pb2a, const void* pb2b,
    const void* pWfc, const void* pbfc, const int* __restrict__ flags,
    ushort_t* __restrict__ xout, ushort_t* __restrict__ wpout,
    int* __restrict__ batch32, float* __restrict__ params,
    int* __restrict__ cnt, int* __restrict__ ell) {
    int b = blockIdx.x;
    int tid = threadIdx.x;
    if (b < EDGE_BLOCKS) {
        int group = b & (EDGE_GROUPS - 1);
        int chunk = b >> 3;
        int lo = group * EDGE_BUCKET;
        int hi = lo + EDGE_BUCKET;
        const int* p = (const int*)eiraw;
        int i64 = flags[1];
#pragma unroll
        for (int i = 0; i < EDGE_CHUNK; i += 256) {
            int e = chunk * EDGE_CHUNK + i + tid;
            if (e < N_EDGES) {
                int d = i64 ? p[2 * (N_EDGES + e)] : p[N_EDGES + e];
                if (d >= lo && d < hi) {
                    int s = i64 ? p[2 * e] : p[e];
                    int slot = atomicAdd(&cnt[d], 1);
                    if (slot < ELL_CAP) ell[d * ELL_CAP + slot] = s;
                }
            }
        }
    } else if (b < EDGE_BLOCKS + PREP_X_BLOCKS) {
        if (flags[0]) {  // only f32 input needs conversion; bf16 is read in place
            int i = (b - EDGE_BLOCKS) * 256 + tid;
            if (i < N_NODES * DIM / 4) {
                float4 v = ((const float4*)xraw)[i];
                ushort4 o;
                o.x = f2bf(v.x); o.y = f2bf(v.y); o.z = f2bf(v.z); o.w = f2bf(v.w);
                ((ushort4*)xout)[i] = o;
            }
        }
    } else if (b < EDGE_BLOCKS + PREP_X_BLOCKS + PREP_W_BLOCKS) {
        int gidx = (b - EDGE_BLOCKS - PREP_X_BLOCKS) * 256 + tid;  // 0..65535
        int which = gidx >> 14;
        const void* W = (which == 0) ? W0 : (which == 1) ? W1 : (which == 2) ? W2 : W3;
        int idx = gidx & 16383;
        int j = idx & 7;
        int L = (idx >> 3) & 63;
        int t = (idx >> 9) & 7;
        int s = idx >> 12;
        int k = s * 32 + (L >> 4) * 8 + j;
        int n = t * 16 + (L & 15);
        int off = k * DIM + n;
        wpout[gidx] = flags[0] ? f2bf(((const float*)W)[off]) : ((const ushort_t*)W)[off];
    } else if (b < EDGE_BLOCKS + PREP_X_BLOCKS + PREP_W_BLOCKS + PREP_B_BLOCKS) {
        int i = (b - EDGE_BLOCKS - PREP_X_BLOCKS - PREP_W_BLOCKS) * 256 + tid;
        if (i < N_NODES) {
            const int* p = (const int*)braw;
            batch32[i] = flags[1] ? p[2 * i] : p[i];
        }
    } else {
        for (int i = tid; i < 770; i += 256) {
            const void* srcp;
            int j;
            if (i < 128)      { srcp = pb1a; j = i; }
            else if (i < 256) { srcp = pb1b; j = i - 128; }
            else if (i < 384) { srcp = pb2a; j = i - 256; }
            else if (i < 512) { srcp = pb2b; j = i - 384; }
            else if (i < 768) { srcp = pWfc; j = i - 512; }
            else              { srcp = pbfc; j = i - 768; }
            params[i] = flags[0] ? ((const float*)srcp)[j] : bf2f(((const ushort_t*)srcp)[j]);
        }
    }
}

// ---------------- fused gather: o = bf16(f32sum(feat[n] + sum feat[src_j])) ------
// Quarter-wave (16 lanes) per node, uint4 (8 bf16) per lane. Same per-dim
// summation order and single RNE rounding as the old standalone agg_kernel.
__device__ __forceinline__ uint4 gather_node_row(const uint4* __restrict__ fp,
                                                 const int* __restrict__ deg,
                                                 const int* __restrict__ ell,
                                                 int n, int lane) {
    uint4 v = fp[(size_t)n * 16 + lane];
    float a0 = bf2f((ushort_t)(v.x & 0xffff));
    float a1 = bf2f((ushort_t)(v.x >> 16));
    float a2 = bf2f((ushort_t)(v.y & 0xffff));
    float a3 = bf2f((ushort_t)(v.y >> 16));
    float a4 = bf2f((ushort_t)(v.z & 0xffff));
    float a5 = bf2f((ushort_t)(v.z >> 16));
    float a6 = bf2f((ushort_t)(v.w & 0xffff));
    float a7 = bf2f((ushort_t)(v.w >> 16));
    int e1 = deg[n];
    if (e1 > ELL_CAP) e1 = ELL_CAP;
    const int* __restrict__ row = ell + (size_t)n * ELL_CAP;
    int j = 0;
#define ACC8(V) \
    a0 += bf2f((ushort_t)((V).x & 0xffff)); a1 += bf2f((ushort_t)((V).x >> 16)); \
    a2 += bf2f((ushort_t)((V).y & 0xffff)); a3 += bf2f((ushort_t)((V).y >> 16)); \
    a4 += bf2f((ushort_t)((V).z & 0xffff)); a5 += bf2f((ushort_t)((V).z >> 16)); \
    a6 += bf2f((ushort_t)((V).w & 0xffff)); a7 += bf2f((ushort_t)((V).w >> 16));
    for (; j + 8 <= e1; j += 8) {
        int s0 = row[j],     s1 = row[j + 1], s2 = row[j + 2], s3 = row[j + 3];
        int s4 = row[j + 4], s5 = row[j + 5], s6 = row[j + 6], s7 = row[j + 7];
        uint4 g0 = fp[(size_t)s0 * 16 + lane];
        uint4 g1 = fp[(size_t)s1 * 16 + lane];
        uint4 g2 = fp[(size_t)s2 * 16 + lane];
        uint4 g3 = fp[(size_t)s3 * 16 + lane];
        uint4 g4 = fp[(size_t)s4 * 16 + lane];
        uint4 g5 = fp[(size_t)s5 * 16 + lane];
        uint4 g6 = fp[(size_t)s6 * 16 + lane];
        uint4 g7 = fp[(size_t)s7 * 16 + lane];
        ACC8(g0) ACC8(g1) ACC8(g2) ACC8(g3)
        ACC8(g4) ACC8(g5) ACC8(g6) ACC8(g7)
    }
    for (; j + 4 <= e1; j += 4) {
        int s0 = row[j], s1 = row[j + 1], s2 = row[j + 2], s3 = row[j + 3];
        uint4 g0 = fp[(size_t)s0 * 16 + lane];
        uint4 g1 = fp[(size_t)s1 * 16 + lane];
        uint4 g2 = fp[(size_t)s2 * 16 + lane];
        uint4 g3 = fp[(size_t)s3 * 16 + lane];
        ACC8(g0) ACC8(g1) ACC8(g2) ACC8(g3)
    }
    for (; j < e1; ++j) {
        int s = row[j];
        uint4 g0 = fp[(size_t)s * 16 + lane];
        ACC8(g0)
    }
#undef ACC8
    uint4 o;
    o.x = (uint_t)f2bf(a0) | ((uint_t)f2bf(a1) << 16);
    o.y = (uint_t)f2bf(a2) | ((uint_t)f2bf(a3) << 16);
    o.z = (uint_t)f2bf(a4) | ((uint_t)f2bf(a5) << 16);
    o.w = (uint_t)f2bf(a6) | ((uint_t)f2bf(a7) << 16);
    return o;
}

// Stage 64 aggregated rows into As (4 passes x 16 nodes, 16 lanes/node).
__device__ __forceinline__ void stage_gather(const ushort_t* feat,
                                             const int* __restrict__ deg,
                                             const int* __restrict__ ell,
                                             int row0, int tid, ushort_t* As) {
    const uint4* fp = reinterpret_cast<const uint4*>(feat);
    int lane = tid & 15;
    int sub = tid >> 4;  // 0..15
#pragma unroll
    for (int p = 0; p < 4; ++p) {
        int r = p * 16 + sub;
        int n = row0 + r;
        uint4 o = make_uint4(0u, 0u, 0u, 0u);
        if (n < N_NODES) o = gather_node_row(fp, deg, ell, n, lane);
        *reinterpret_cast<uint4*>(&As[r * LDA + lane * 8]) = o;
    }
}

// ---------------- fused agg + MLP layer 1: hout = relu(relu((x+agg)@Wa+ba)@Wb+bb)
__global__ __launch_bounds__(256) void mlp_kernel(const ushort_t* __restrict__ hX,
                                                  const void* __restrict__ xraw,
                                                  const int* __restrict__ flags,
                                                  const int* __restrict__ deg,
                                                  const int* __restrict__ ell,
                                                  const ushort_t* __restrict__ wpA,
                                                  const float* __restrict__ ba,
                                                  const ushort_t* __restrict__ wpB,
                                                  const float* __restrict__ bb,
                                                  ushort_t* __restrict__ hout) {
    __shared__ ushort_t As[64 * LDA];
    int tid = threadIdx.x;
    int wave = tid >> 6;
    int lane = tid & 63;
    int quad = lane >> 4;
    int cl = lane & 15;
    int row0 = blockIdx.x * 64;

    const ushort_t* feat = flags[0] ? hX : (const ushort_t*)xraw;
    stage_gather(feat, deg, ell, row0, tid, As);

    bf16x8 B1[2][4], B2[2][4];
#pragma unroll
    for (int ti = 0; ti < 2; ++ti) {
        int t = 2 * wave + ti;
#pragma unroll
        for (int s = 0; s < 4; ++s) {
            B1[ti][s] = as_bf16x8(reinterpret_cast<const uint4*>(wpA)[(s * 8 + t) * 64 + lane]);
            B2[ti][s] = as_bf16x8(reinterpret_cast<const uint4*>(wpB)[(s * 8 + t) * 64 + lane]);
        }
    }
    __syncthreads();

    f32x4 acc[4][2];
#pragma unroll
    for (int m = 0; m < 4; ++m)
#pragma unroll
        for (int ti = 0; ti < 2; ++ti)
#pragma unroll
            for (int r = 0; r < 4; ++r) acc[m][ti][r] = 0.f;

#pragma unroll
    for (int s = 0; s < 4; ++s) {
#pragma unroll
        for (int m = 0; m < 4; ++m) {
            bf16x8 a = *reinterpret_cast<const bf16x8*>(&As[(m * 16 + cl) * LDA + s * 32 + quad * 8]);
#pragma unroll
            for (int ti = 0; ti < 2; ++ti)
                acc[m][ti] = __builtin_amdgcn_mfma_f32_16x16x32_bf16(a, B1[ti][s], acc[m][ti], 0, 0, 0);
        }
    }
    __syncthreads();

#pragma unroll
    for (int ti = 0; ti < 2; ++ti) {
        int col = 32 * wave + ti * 16 + cl;
        float bv = ba[col];
#pragma unroll
        for (int m = 0; m < 4; ++m)
#pragma unroll
            for (int r = 0; r < 4; ++r) {
                float v = acc[m][ti][r] + bv;
                As[(m * 16 + quad * 4 + r) * LDA + col] = f2bf(fmaxf(v, 0.f));
            }
    }
    __syncthreads();

#pragma unroll
    for (int m = 0; m < 4; ++m)
#pragma unroll
        for (int ti = 0; ti < 2; ++ti)
#pragma unroll
            for (int r = 0; r < 4; ++r) acc[m][ti][r] = 0.f;

#pragma unroll
    for (int s = 0; s < 4; ++s) {
#pragma unroll
        for (int m = 0; m < 4; ++m) {
            bf16x8 a = *reinterpret_cast<const bf16x8*>(&As[(m * 16 + cl) * LDA + s * 32 + quad * 8]);
#pragma unroll
            for (int ti = 0; ti < 2; ++ti)
                acc[m][ti] = __builtin_amdgcn_mfma_f32_16x16x32_bf16(a, B2[ti][s], acc[m][ti], 0, 0, 0);
        }
    }

#pragma unroll
    for (int ti = 0; ti < 2; ++ti) {
        int col = 32 * wave + ti * 16 + cl;
        float bv = bb[col];
#pragma unroll
        for (int m = 0; m < 4; ++m)
#pragma unroll
            for (int r = 0; r < 4; ++r) {
                int gr = row0 + m * 16 + quad * 4 + r;
                if (gr < N_NODES) {
                    float v = acc[m][ti][r] + bv;
                    hout[(size_t)gr * DIM + col] = f2bf(fmaxf(v, 0.f));
                }
            }
    }
}

// ---------------- fused agg + MLP layer 2 + per-graph pooling ----------------
__global__ __launch_bounds__(256) void mlp_pool_kernel(const ushort_t* __restrict__ hin,
                                                       const int* __restrict__ deg,
                                                       const int* __restrict__ ell,
                                                       const ushort_t* __restrict__ wpA,
                                                       const float* __restrict__ ba,
                                                       const ushort_t* __restrict__ wpB,
                                                       const float* __restrict__ bb,
                                                       const int* __restrict__ batch32,
                                                       float* __restrict__ gsum) {
    __shared__ ushort_t As[64 * LDA];
    int tid = threadIdx.x;
    int wave = tid >> 6;
    int lane = tid & 63;
    int quad = lane >> 4;
    int cl = lane & 15;
    int row0 = blockIdx.x * 64;

    stage_gather(hin, deg, ell, row0, tid, As);

    bf16x8 B1[2][4], B2[2][4];
#pragma unroll
    for (int ti = 0; ti < 2; ++ti) {
        int t = 2 * wave + ti;
#pragma unroll
        for (int s = 0; s < 4; ++s) {
            B1[ti][s] = as_bf16x8(reinterpret_cast<const uint4*>(wpA)[(s * 8 + t) * 64 + lane]);
            B2[ti][s] = as_bf16x8(reinterpret_cast<const uint4*>(wpB)[(s * 8 + t) * 64 + lane]);
        }
    }
    __syncthreads();

    f32x4 acc[4][2];
#pragma unroll
    for (int m = 0; m < 4; ++m)
#pragma unroll
        for (int ti = 0; ti < 2; ++ti)
#pragma unroll
            for (int r = 0; r < 4; ++r) acc[m][ti][r] = 0.f;

#pragma unroll
    for (int s = 0; s < 4; ++s) {
#pragma unroll
        for (int m = 0; m < 4; ++m) {
            bf16x8 a = *reinterpret_cast<const bf16x8*>(&As[(m * 16 + cl) * LDA + s * 32 + quad * 8]);
#pragma unroll
            for (int ti = 0; ti < 2; ++ti)
                acc[m][ti] = __builtin_amdgcn_mfma_f32_16x16x32_bf16(a, B1[ti][s], acc[m][ti], 0, 0, 0);
        }
    }
    __syncthreads();

#pragma unroll
    for (int ti = 0; ti < 2; ++ti) {
        int col = 32 * wave + ti * 16 + cl;
        float bv = ba[col];
#pragma unroll
        for (int m = 0; m < 4; ++m)
#pragma unroll
            for (int r = 0; r < 4; ++r) {
                float v = acc[m][ti][r] + bv;
                As[(m * 16 + quad * 4 + r) * LDA + col] = f2bf(fmaxf(v, 0.f));
            }
    }
    __syncthreads();

#pragma unroll
    for (int m = 0; m < 4; ++m)
#pragma unroll
        for (int ti = 0; ti < 2; ++ti)
#pragma unroll
            for (int r = 0; r < 4; ++r) acc[m][ti][r] = 0.f;

#pragma unroll
    for (int s = 0; s < 4; ++s) {
#pragma unroll
        for (int m = 0; m < 4; ++m) {
            bf16x8 a = *reinterpret_cast<const bf16x8*>(&As[(m * 16 + cl) * LDA + s * 32 + quad * 8]);
#pragma unroll
            for (int ti = 0; ti < 2; ++ti)
                acc[m][ti] = __builtin_amdgcn_mfma_f32_16x16x32_bf16(a, B2[ti][s], acc[m][ti], 0, 0, 0);
        }
    }
    __syncthreads();  // all As reads of GEMM2 done before epilogue overwrite

#pragma unroll
    for (int ti = 0; ti < 2; ++ti) {
        int col = 32 * wave + ti * 16 + cl;
        float bv = bb[col];
#pragma unroll
        for (int m = 0; m < 4; ++m)
#pragma unroll
            for (int r = 0; r < 4; ++r) {
                float v = acc[m][ti][r] + bv;
                As[(m * 16 + quad * 4 + r) * LDA + col] = f2bf(fmaxf(v, 0.f));
            }
    }
    __syncthreads();

    // pooling: thread t handles col c over 32 rows; flush per graph segment
    int c = tid & 127;
    int rbase = (tid >> 7) * 32;
    float accp = 0.f;
    int curg = -1;
    for (int r = rbase; r < rbase + 32; ++r) {
        int gr = row0 + r;
        if (gr >= N_NODES) break;
        int g = batch32[gr];
        if (g != curg) {
            if (curg >= 0) atomicAdd(&gsum[curg * DIM + c], accp);
            curg = g;
            accp = 0.f;
        }
        accp += bf2f(As[r * LDA + c]);
    }
    if (curg >= 0) atomicAdd(&gsum[curg * DIM + c], accp);
}

// ---------------- final FC: out[g] = (gsum[g]/count[g]) @ Wfc + bfc ----------------
__global__ __launch_bounds__(64) void fc_kernel(const float* __restrict__ gsum,
                                                const int* __restrict__ batch,
                                                const float* __restrict__ params,
                                                const int* __restrict__ flags,
                                                void* __restrict__ out) {
    int g = blockIdx.x;
    int l = threadIdx.x;
    int lo = 0, hi = N_NODES;
    while (lo < hi) { int mid = (lo + hi) >> 1; if (batch[mid] < g) lo = mid + 1; else hi = mid; }
    int start = lo;
    hi = N_NODES;
    while (lo < hi) { int mid = (lo + hi) >> 1; if (batch[mid] < g + 1) lo = mid + 1; else hi = mid; }
    int cnt = lo - start;
    float inv = 1.0f / (float)(cnt > 0 ? cnt : 1);
    float m0 = gsum[g * DIM + l] * inv;
    float m1 = gsum[g * DIM + 64 + l] * inv;
    float p0 = m0 * params[512 + l * 2 + 0] + m1 * params[512 + (64 + l) * 2 + 0];
    float p1 = m0 * params[512 + l * 2 + 1] + m1 * params[512 + (64 + l) * 2 + 1];
#pragma unroll
    for (int off = 32; off > 0; off >>= 1) {
        p0 += __shfl_down(p0, off, 64);
        p1 += __shfl_down(p1, off, 64);
    }
    if (l == 0) {
        float o0 = p0 + params[768];
        float o1 = p1 + params[769];
        if (flags[0]) {
            ((float*)out)[g * 2 + 0] = o0;
            ((float*)out)[g * 2 + 1] = o1;
        } else {
            ((ushort_t*)out)[g * 2 + 0] = f2bf(o0);
            ((ushort_t*)out)[g * 2 + 1] = f2bf(o1);
        }
    }
}

extern "C" void kernel_launch(void* const* d_in, const int* in_sizes, int n_in,
                              void* d_out, int out_size, void* d_ws, size_t ws_size,
                              hipStream_t stream) {
    const void* x = d_in[0];
    const void* ei = d_in[1];
    const void* batch = d_in[2];
    const void* W1a = d_in[3];
    const void* b1a = d_in[4];
    const void* W1b = d_in[5];
    const void* b1b = d_in[6];
    const void* W2a = d_in[7];
    const void* b2a = d_in[8];
    const void* W2b = d_in[9];
    const void* b2b = d_in[10];
    const void* Wfc = d_in[11];
    const void* bfc = d_in[12];

    // Workspace layout (~40 MB, all chunks 16B-aligned)
    char* base = (char*)d_ws;
    ushort_t* hX = (ushort_t*)base;   base += (size_t)N_NODES * DIM * 2;       // 12.8 MB (f32 input only)
    ushort_t* hA = (ushort_t*)base;   base += (size_t)N_NODES * DIM * 2;       // 12.8 MB
    int* ell = (int*)base;            base += (size_t)N_NODES * ELL_CAP * 4;   // 12.8 MB
    int* cnt = (int*)base;            base += (size_t)N_NODES * 4;
    int* batch32 = (int*)base;        base += (size_t)N_NODES * 4;
    ushort_t* wp = (ushort_t*)base;   base += 4 * 16384 * 2;
    float* params = (float*)base;     base += 772 * 4;
    float* gsum = (float*)base;       base += (size_t)NUM_GRAPHS * DIM * 4;    // 256 KB
    int* flags = (int*)base;          base += 16;

    ushort_t* wpA1 = wp;
    ushort_t* wpB1 = wp + 16384;
    ushort_t* wpA2 = wp + 2 * 16384;
    ushort_t* wpB2 = wp + 3 * 16384;

    // Zero degree+gsum, detect dtypes; 256 blocks covers 65536 threads
    zero_detect_kernel<<<256, 256, 0, stream>>>(cnt, gsum, x, ei, flags);
    // Merged canonicalization (edges->ELL XCD-bucketed, x-conv, weights, batch, params)
    prep_all_kernel<<<PREP_TOTAL, 256, 0, stream>>>(x, batch, ei, W1a, W1b, W2a, W2b,
                                                    b1a, b1b, b2a, b2b, Wfc, bfc, flags,
                                                    hX, wp, batch32, params, cnt, ell);

    // Layer 1: fused agg(x)+MLP -> hA
    mlp_kernel<<<(N_NODES + 63) / 64, 256, 0, stream>>>(hX, x, flags, cnt, ell,
                                                        wpA1, params + 0, wpB1, params + 128, hA);
    // Layer 2: fused agg(hA)+MLP+pool -> gsum (no intermediate global write)
    mlp_pool_kernel<<<(N_NODES + 63) / 64, 256, 0, stream>>>(hA, cnt, ell,
                                                             wpA2, params + 256, wpB2, params + 384,
                                                             batch32, gsum);
    // Final FC from pooled sums
    fc_kernel<<<NUM_GRAPHS, 64, 0, stream>>>(gsum, batch32, params, flags, d_out);
}

// Round 3
// 240.745 us; speedup vs baseline: 1.0538x; 1.0538x over previous
//
#include <hip/hip_runtime.h>

typedef unsigned short ushort_t;
typedef unsigned int uint_t;

typedef __bf16 bf16x8 __attribute__((ext_vector_type(8)));
typedef float f32x4 __attribute__((ext_vector_type(4)));

#define N_NODES 50000
#define N_EDGES 800000
#define DIM 128
#define NUM_GRAPHS 512
#define LDA 136  // padded LDS row stride in bf16 elems (128+8)

// ELL adjacency: fixed 64 slots per node (in-degree ~Poisson(16), max ~35;
// P(deg>64) astronomically small. Guarded anyway: overflow slots dropped.)
#define ELL_CAP 64

// XCD-bucketed edge scatter: 8 dst-range groups, group = blockIdx&7 so each
// group's cnt/ell region (25KB + 1.6MB) stays in ONE XCD's L2 (round-robin
// block->XCD dispatch). Kills atomic line ping-pong + write amplification.
#define EDGE_GROUPS 8
#define EDGE_BUCKET ((N_NODES + EDGE_GROUPS - 1) / EDGE_GROUPS)  // 6250
#define EDGE_CHUNK 2048
#define EDGE_CHUNKS ((N_EDGES + EDGE_CHUNK - 1) / EDGE_CHUNK)    // 391
#define EDGE_BLOCKS (EDGE_CHUNKS * EDGE_GROUPS)                  // 3128

// prep_all block ranges (edge blocks first: they are the critical path)
#define PREP_X_BLOCKS 6250                    // conv_x: only does work when f32 input
#define PREP_W_BLOCKS 256                     // wperm: 65536 / 256
#define PREP_B_BLOCKS 196                     // batch: 50000 / 256
#define PREP_TOTAL (EDGE_BLOCKS + PREP_X_BLOCKS + PREP_W_BLOCKS + PREP_B_BLOCKS + 1)

__device__ __forceinline__ float bf2f(ushort_t u) {
    return __uint_as_float(((uint_t)u) << 16);
}
__device__ __forceinline__ ushort_t f2bf(float f) {
    uint_t u = __float_as_uint(f);
    u = (u + 0x7FFF + ((u >> 16) & 1)) >> 16;  // RNE
    return (ushort_t)u;
}
__device__ __forceinline__ bf16x8 as_bf16x8(uint4 v) {
    return __builtin_bit_cast(bf16x8, v);
}

// ---------------- zero (degree + gsum) + dtype detection (merged) ----------------
__global__ void zero_detect_kernel(int* cnt, float* gsum, const void* xraw,
                                   const void* eiraw, int* flags) {
    int i = blockIdx.x * 256 + threadIdx.x;
    if (i < N_NODES) cnt[i] = 0;
    if (i < NUM_GRAPHS * DIM) gsum[i] = 0.f;
    if (i == 0) {
        const ushort_t* u = (const ushort_t*)xraw;
        int extreme = 0;
        for (int k = 0; k < 128; ++k) {
            int e = (u[k] >> 7) & 0xFF;
            if (e >= 0xC0) extreme++;  // |x| >= 2^65: impossible for bf16 N(0,1)
        }
        flags[0] = (extreme > 8) ? 1 : 0;
        const int* p = (const int*)eiraw;
        int nonzero = 0;
        for (int k = 1; k < 64; k += 2) nonzero += (p[k] != 0);
        flags[1] = (nonzero == 0) ? 1 : 0;  // all high-halves zero => int64
    }
}

// ---------------- merged canonicalization + XCD-bucketed ELL build ----------------
__global__ __launch_bounds__(256) void prep_all_kernel(
    const void* xraw, const void* braw, const void* eiraw,
    const void* W0, const void* W1, const void* W2, const void* W3,
    const void* pb1a, const void* pb1b, const void* pb2a, const void* pb2b,
    const void* pWfc, const void* pbfc, const int* __restrict__ flags,
    ushort_t* __restrict__ xout, ushort_t* __restrict__ wpout,
    int* __restrict__ batch32, float* __restrict__ params,
    int* __restrict__ cnt, int* __restrict__ ell) {
    int b = blockIdx.x;
    int tid = threadIdx.x;
    if (b < EDGE_BLOCKS) {
        int group = b & (EDGE_GROUPS - 1);
        int chunk = b >> 3;
        int lo = group * EDGE_BUCKET;
        int hi = lo + EDGE_BUCKET;
        const int* p = (const int*)eiraw;
        int i64 = flags[1];
#pragma unroll
        for (int i = 0; i < EDGE_CHUNK; i += 256) {
            int e = chunk * EDGE_CHUNK + i + tid;
            if (e < N_EDGES) {
                int d = i64 ? p[2 * (N_EDGES + e)] : p[N_EDGES + e];
                if (d >= lo && d < hi) {
                    int s = i64 ? p[2 * e] : p[e];
                    int slot = atomicAdd(&cnt[d], 1);
                    if (slot < ELL_CAP) ell[d * ELL_CAP + slot] = s;
                }
            }
        }
    } else if (b < EDGE_BLOCKS + PREP_X_BLOCKS) {
        if (flags[0]) {  // only f32 input needs conversion; bf16 is read in place
            int i = (b - EDGE_BLOCKS) * 256 + tid;
            if (i < N_NODES * DIM / 4) {
                float4 v = ((const float4*)xraw)[i];
                ushort4 o;
                o.x = f2bf(v.x); o.y = f2bf(v.y); o.z = f2bf(v.z); o.w = f2bf(v.w);
                ((ushort4*)xout)[i] = o;
            }
        }
    } else if (b < EDGE_BLOCKS + PREP_X_BLOCKS + PREP_W_BLOCKS) {
        int gidx = (b - EDGE_BLOCKS - PREP_X_BLOCKS) * 256 + tid;  // 0..65535
        int which = gidx >> 14;
        const void* W = (which == 0) ? W0 : (which == 1) ? W1 : (which == 2) ? W2 : W3;
        int idx = gidx & 16383;
        int j = idx & 7;
        int L = (idx >> 3) & 63;
        int t = (idx >> 9) & 7;
        int s = idx >> 12;
        int k = s * 32 + (L >> 4) * 8 + j;
        int n = t * 16 + (L & 15);
        int off = k * DIM + n;
        wpout[gidx] = flags[0] ? f2bf(((const float*)W)[off]) : ((const ushort_t*)W)[off];
    } else if (b < EDGE_BLOCKS + PREP_X_BLOCKS + PREP_W_BLOCKS + PREP_B_BLOCKS) {
        int i = (b - EDGE_BLOCKS - PREP_X_BLOCKS - PREP_W_BLOCKS) * 256 + tid;
        if (i < N_NODES) {
            const int* p = (const int*)braw;
            batch32[i] = flags[1] ? p[2 * i] : p[i];
        }
    } else {
        for (int i = tid; i < 770; i += 256) {
            const void* srcp;
            int j;
            if (i < 128)      { srcp = pb1a; j = i; }
            else if (i < 256) { srcp = pb1b; j = i - 128; }
            else if (i < 384) { srcp = pb2a; j = i - 256; }
            else if (i < 512) { srcp = pb2b; j = i - 384; }
            else if (i < 768) { srcp = pWfc; j = i - 512; }
            else              { srcp = pbfc; j = i - 768; }
            params[i] = flags[0] ? ((const float*)srcp)[j] : bf2f(((const ushort_t*)srcp)[j]);
        }
    }
}

// ---------------- aggregation: h[n] = feat[n] + sum_{j in in-edges} feat[src_j] ----
// Standalone (NOT fused into the GEMM): 16 nodes/block x 3125 blocks gives
// ~12 blocks/CU -> full 32-wave occupancy to hide random-gather latency.
// Round-2 lesson: fusing this into the 782-block MLP grid dropped occupancy
// to 20% and cost +25us. Quarter-wave (16 lanes) per node, uint4 per lane,
// unroll-8 = 32 gathers in flight per wave.
__global__ __launch_bounds__(256) void agg_kernel(const ushort_t* __restrict__ featA,
                                                  const void* __restrict__ featB,
                                                  const int* __restrict__ flags,
                                                  const int* __restrict__ deg,
                                                  const int* __restrict__ ell,
                                                  ushort_t* __restrict__ hout) {
    int n = blockIdx.x * 16 + (threadIdx.x >> 4);
    int lane = threadIdx.x & 15;
    if (n >= N_NODES) return;
    // flags==nullptr -> use featA; else select converted vs raw-bf16 input
    const ushort_t* feat = featA;
    if (flags && !flags[0]) feat = (const ushort_t*)featB;
    const uint4* fp = reinterpret_cast<const uint4*>(feat);  // row = 16 x uint4
    uint4 v = fp[(size_t)n * 16 + lane];
    float a0 = bf2f((ushort_t)(v.x & 0xffff));
    float a1 = bf2f((ushort_t)(v.x >> 16));
    float a2 = bf2f((ushort_t)(v.y & 0xffff));
    float a3 = bf2f((ushort_t)(v.y >> 16));
    float a4 = bf2f((ushort_t)(v.z & 0xffff));
    float a5 = bf2f((ushort_t)(v.z >> 16));
    float a6 = bf2f((ushort_t)(v.w & 0xffff));
    float a7 = bf2f((ushort_t)(v.w >> 16));
    int e1 = deg[n];
    if (e1 > ELL_CAP) e1 = ELL_CAP;
    const int* __restrict__ row = ell + (size_t)n * ELL_CAP;
    int j = 0;
#define ACC8(V) \
    a0 += bf2f((ushort_t)((V).x & 0xffff)); a1 += bf2f((ushort_t)((V).x >> 16)); \
    a2 += bf2f((ushort_t)((V).y & 0xffff)); a3 += bf2f((ushort_t)((V).y >> 16)); \
    a4 += bf2f((ushort_t)((V).z & 0xffff)); a5 += bf2f((ushort_t)((V).z >> 16)); \
    a6 += bf2f((ushort_t)((V).w & 0xffff)); a7 += bf2f((ushort_t)((V).w >> 16));
    for (; j + 8 <= e1; j += 8) {
        int s0 = row[j],     s1 = row[j + 1], s2 = row[j + 2], s3 = row[j + 3];
        int s4 = row[j + 4], s5 = row[j + 5], s6 = row[j + 6], s7 = row[j + 7];
        uint4 g0 = fp[(size_t)s0 * 16 + lane];
        uint4 g1 = fp[(size_t)s1 * 16 + lane];
        uint4 g2 = fp[(size_t)s2 * 16 + lane];
        uint4 g3 = fp[(size_t)s3 * 16 + lane];
        uint4 g4 = fp[(size_t)s4 * 16 + lane];
        uint4 g5 = fp[(size_t)s5 * 16 + lane];
        uint4 g6 = fp[(size_t)s6 * 16 + lane];
        uint4 g7 = fp[(size_t)s7 * 16 + lane];
        ACC8(g0) ACC8(g1) ACC8(g2) ACC8(g3)
        ACC8(g4) ACC8(g5) ACC8(g6) ACC8(g7)
    }
    for (; j + 4 <= e1; j += 4) {
        int s0 = row[j], s1 = row[j + 1], s2 = row[j + 2], s3 = row[j + 3];
        uint4 g0 = fp[(size_t)s0 * 16 + lane];
        uint4 g1 = fp[(size_t)s1 * 16 + lane];
        uint4 g2 = fp[(size_t)s2 * 16 + lane];
        uint4 g3 = fp[(size_t)s3 * 16 + lane];
        ACC8(g0) ACC8(g1) ACC8(g2) ACC8(g3)
    }
    for (; j < e1; ++j) {
        int s = row[j];
        uint4 g0 = fp[(size_t)s * 16 + lane];
        ACC8(g0)
    }
#undef ACC8
    uint4 o;
    o.x = (uint_t)f2bf(a0) | ((uint_t)f2bf(a1) << 16);
    o.y = (uint_t)f2bf(a2) | ((uint_t)f2bf(a3) << 16);
    o.z = (uint_t)f2bf(a4) | ((uint_t)f2bf(a5) << 16);
    o.w = (uint_t)f2bf(a6) | ((uint_t)f2bf(a7) << 16);
    reinterpret_cast<uint4*>(hout)[(size_t)n * 16 + lane] = o;
}

// ---------------- fused MLP layer 1: hout = relu(relu(hin@Wa+ba)@Wb+bb) --------
__global__ __launch_bounds__(256) void mlp_kernel(const ushort_t* __restrict__ hin,
                                                  const ushort_t* __restrict__ wpA,
                                                  const float* __restrict__ ba,
                                                  const ushort_t* __restrict__ wpB,
                                                  const float* __restrict__ bb,
                                                  ushort_t* __restrict__ hout) {
    __shared__ ushort_t As[64 * LDA];
    int tid = threadIdx.x;
    int wave = tid >> 6;
    int lane = tid & 63;
    int quad = lane >> 4;
    int cl = lane & 15;
    int row0 = blockIdx.x * 64;

    bf16x8 B1[2][4], B2[2][4];
#pragma unroll
    for (int ti = 0; ti < 2; ++ti) {
        int t = 2 * wave + ti;
#pragma unroll
        for (int s = 0; s < 4; ++s) {
            B1[ti][s] = as_bf16x8(reinterpret_cast<const uint4*>(wpA)[(s * 8 + t) * 64 + lane]);
            B2[ti][s] = as_bf16x8(reinterpret_cast<const uint4*>(wpB)[(s * 8 + t) * 64 + lane]);
        }
    }

    for (int i = tid; i < 64 * 16; i += 256) {
        int r = i >> 4, c8 = i & 15;
        uint4 v = make_uint4(0u, 0u, 0u, 0u);
        int gr = row0 + r;
        if (gr < N_NODES)
            v = reinterpret_cast<const uint4*>(hin + (size_t)gr * DIM)[c8];
        *reinterpret_cast<uint4*>(&As[r * LDA + c8 * 8]) = v;
    }
    __syncthreads();

    f32x4 acc[4][2];
#pragma unroll
    for (int m = 0; m < 4; ++m)
#pragma unroll
        for (int ti = 0; ti < 2; ++ti)
#pragma unroll
            for (int r = 0; r < 4; ++r) acc[m][ti][r] = 0.f;

#pragma unroll
    for (int s = 0; s < 4; ++s) {
#pragma unroll
        for (int m = 0; m < 4; ++m) {
            bf16x8 a = *reinterpret_cast<const bf16x8*>(&As[(m * 16 + cl) * LDA + s * 32 + quad * 8]);
#pragma unroll
            for (int ti = 0; ti < 2; ++ti)
                acc[m][ti] = __builtin_amdgcn_mfma_f32_16x16x32_bf16(a, B1[ti][s], acc[m][ti], 0, 0, 0);
        }
    }
    __syncthreads();

#pragma unroll
    for (int ti = 0; ti < 2; ++ti) {
        int col = 32 * wave + ti * 16 + cl;
        float bv = ba[col];
#pragma unroll
        for (int m = 0; m < 4; ++m)
#pragma unroll
            for (int r = 0; r < 4; ++r) {
                float v = acc[m][ti][r] + bv;
                As[(m * 16 + quad * 4 + r) * LDA + col] = f2bf(fmaxf(v, 0.f));
            }
    }
    __syncthreads();

#pragma unroll
    for (int m = 0; m < 4; ++m)
#pragma unroll
        for (int ti = 0; ti < 2; ++ti)
#pragma unroll
            for (int r = 0; r < 4; ++r) acc[m][ti][r] = 0.f;

#pragma unroll
    for (int s = 0; s < 4; ++s) {
#pragma unroll
        for (int m = 0; m < 4; ++m) {
            bf16x8 a = *reinterpret_cast<const bf16x8*>(&As[(m * 16 + cl) * LDA + s * 32 + quad * 8]);
#pragma unroll
            for (int ti = 0; ti < 2; ++ti)
                acc[m][ti] = __builtin_amdgcn_mfma_f32_16x16x32_bf16(a, B2[ti][s], acc[m][ti], 0, 0, 0);
        }
    }

#pragma unroll
    for (int ti = 0; ti < 2; ++ti) {
        int col = 32 * wave + ti * 16 + cl;
        float bv = bb[col];
#pragma unroll
        for (int m = 0; m < 4; ++m)
#pragma unroll
            for (int r = 0; r < 4; ++r) {
                int gr = row0 + m * 16 + quad * 4 + r;
                if (gr < N_NODES) {
                    float v = acc[m][ti][r] + bv;
                    hout[(size_t)gr * DIM + col] = f2bf(fmaxf(v, 0.f));
                }
            }
    }
}

// ---------------- fused MLP layer 2 + per-graph pooling ----------------
__global__ __launch_bounds__(256) void mlp_pool_kernel(const ushort_t* __restrict__ hin,
                                                       const ushort_t* __restrict__ wpA,
                                                       const float* __restrict__ ba,
                                                       const ushort_t* __restrict__ wpB,
                                                       const float* __restrict__ bb,
                                                       const int* __restrict__ batch32,
                                                       float* __restrict__ gsum) {
    __shared__ ushort_t As[64 * LDA];
    int tid = threadIdx.x;
    int wave = tid >> 6;
    int lane = tid & 63;
    int quad = lane >> 4;
    int cl = lane & 15;
    int row0 = blockIdx.x * 64;

    bf16x8 B1[2][4], B2[2][4];
#pragma unroll
    for (int ti = 0; ti < 2; ++ti) {
        int t = 2 * wave + ti;
#pragma unroll
        for (int s = 0; s < 4; ++s) {
            B1[ti][s] = as_bf16x8(reinterpret_cast<const uint4*>(wpA)[(s * 8 + t) * 64 + lane]);
            B2[ti][s] = as_bf16x8(reinterpret_cast<const uint4*>(wpB)[(s * 8 + t) * 64 + lane]);
        }
    }

    for (int i = tid; i < 64 * 16; i += 256) {
        int r = i >> 4, c8 = i & 15;
        uint4 v = make_uint4(0u, 0u, 0u, 0u);
        int gr = row0 + r;
        if (gr < N_NODES)
            v = reinterpret_cast<const uint4*>(hin + (size_t)gr * DIM)[c8];
        *reinterpret_cast<uint4*>(&As[r * LDA + c8 * 8]) = v;
    }
    __syncthreads();

    f32x4 acc[4][2];
#pragma unroll
    for (int m = 0; m < 4; ++m)
#pragma unroll
        for (int ti = 0; ti < 2; ++ti)
#pragma unroll
            for (int r = 0; r < 4; ++r) acc[m][ti][r] = 0.f;

#pragma unroll
    for (int s = 0; s < 4; ++s) {
#pragma unroll
        for (int m = 0; m < 4; ++m) {
            bf16x8 a = *reinterpret_cast<const bf16x8*>(&As[(m * 16 + cl) * LDA + s * 32 + quad * 8]);
#pragma unroll
            for (int ti = 0; ti < 2; ++ti)
                acc[m][ti] = __builtin_amdgcn_mfma_f32_16x16x32_bf16(a, B1[ti][s], acc[m][ti], 0, 0, 0);
        }
    }
    __syncthreads();

#pragma unroll
    for (int ti = 0; ti < 2; ++ti) {
        int col = 32 * wave + ti * 16 + cl;
        float bv = ba[col];
#pragma unroll
        for (int m = 0; m < 4; ++m)
#pragma unroll
            for (int r = 0; r < 4; ++r) {
                float v = acc[m][ti][r] + bv;
                As[(m * 16 + quad * 4 + r) * LDA + col] = f2bf(fmaxf(v, 0.f));
            }
    }
    __syncthreads();

#pragma unroll
    for (int m = 0; m < 4; ++m)
#pragma unroll
        for (int ti = 0; ti < 2; ++ti)
#pragma unroll
            for (int r = 0; r < 4; ++r) acc[m][ti][r] = 0.f;

#pragma unroll
    for (int s = 0; s < 4; ++s) {
#pragma unroll
        for (int m = 0; m < 4; ++m) {
            bf16x8 a = *reinterpret_cast<const bf16x8*>(&As[(m * 16 + cl) * LDA + s * 32 + quad * 8]);
#pragma unroll
            for (int ti = 0; ti < 2; ++ti)
                acc[m][ti] = __builtin_amdgcn_mfma_f32_16x16x32_bf16(a, B2[ti][s], acc[m][ti], 0, 0, 0);
        }
    }
    __syncthreads();  // all As reads of GEMM2 done before epilogue overwrite

#pragma unroll
    for (int ti = 0; ti < 2; ++ti) {
        int col = 32 * wave + ti * 16 + cl;
        float bv = bb[col];
#pragma unroll
        for (int m = 0; m < 4; ++m)
#pragma unroll
            for (int r = 0; r < 4; ++r) {
                float v = acc[m][ti][r] + bv;
                As[(m * 16 + quad * 4 + r) * LDA + col] = f2bf(fmaxf(v, 0.f));
            }
    }
    __syncthreads();

    // pooling: thread t handles col c over 32 rows; flush per graph segment
    int c = tid & 127;
    int rbase = (tid >> 7) * 32;
    float accp = 0.f;
    int curg = -1;
    for (int r = rbase; r < rbase + 32; ++r) {
        int gr = row0 + r;
        if (gr >= N_NODES) break;
        int g = batch32[gr];
        if (g != curg) {
            if (curg >= 0) atomicAdd(&gsum[curg * DIM + c], accp);
            curg = g;
            accp = 0.f;
        }
        accp += bf2f(As[r * LDA + c]);
    }
    if (curg >= 0) atomicAdd(&gsum[curg * DIM + c], accp);
}

// ---------------- final FC: out[g] = (gsum[g]/count[g]) @ Wfc + bfc ----------------
__global__ __launch_bounds__(64) void fc_kernel(const float* __restrict__ gsum,
                                                const int* __restrict__ batch,
                                                const float* __restrict__ params,
                                                const int* __restrict__ flags,
                                                void* __restrict__ out) {
    int g = blockIdx.x;
    int l = threadIdx.x;
    int lo = 0, hi = N_NODES;
    while (lo < hi) { int mid = (lo + hi) >> 1; if (batch[mid] < g) lo = mid + 1; else hi = mid; }
    int start = lo;
    hi = N_NODES;
    while (lo < hi) { int mid = (lo + hi) >> 1; if (batch[mid] < g + 1) lo = mid + 1; else hi = mid; }
    int cnt = lo - start;
    float inv = 1.0f / (float)(cnt > 0 ? cnt : 1);
    float m0 = gsum[g * DIM + l] * inv;
    float m1 = gsum[g * DIM + 64 + l] * inv;
    float p0 = m0 * params[512 + l * 2 + 0] + m1 * params[512 + (64 + l) * 2 + 0];
    float p1 = m0 * params[512 + l * 2 + 1] + m1 * params[512 + (64 + l) * 2 + 1];
#pragma unroll
    for (int off = 32; off > 0; off >>= 1) {
        p0 += __shfl_down(p0, off, 64);
        p1 += __shfl_down(p1, off, 64);
    }
    if (l == 0) {
        float o0 = p0 + params[768];
        float o1 = p1 + params[769];
        if (flags[0]) {
            ((float*)out)[g * 2 + 0] = o0;
            ((float*)out)[g * 2 + 1] = o1;
        } else {
            ((ushort_t*)out)[g * 2 + 0] = f2bf(o0);
            ((ushort_t*)out)[g * 2 + 1] = f2bf(o1);
        }
    }
}

extern "C" void kernel_launch(void* const* d_in, const int* in_sizes, int n_in,
                              void* d_out, int out_size, void* d_ws, size_t ws_size,
                              hipStream_t stream) {
    const void* x = d_in[0];
    const void* ei = d_in[1];
    const void* batch = d_in[2];
    const void* W1a = d_in[3];
    const void* b1a = d_in[4];
    const void* W1b = d_in[5];
    const void* b1b = d_in[6];
    const void* W2a = d_in[7];
    const void* b2a = d_in[8];
    const void* W2b = d_in[9];
    const void* b2b = d_in[10];
    const void* Wfc = d_in[11];
    const void* bfc = d_in[12];

    // Workspace layout (~40 MB, all chunks 16B-aligned)
    char* base = (char*)d_ws;
    ushort_t* hX = (ushort_t*)base;   base += (size_t)N_NODES * DIM * 2;       // 12.8 MB (f32 input only)
    ushort_t* hA = (ushort_t*)base;   base += (size_t)N_NODES * DIM * 2;       // 12.8 MB
    int* ell = (int*)base;            base += (size_t)N_NODES * ELL_CAP * 4;   // 12.8 MB
    int* cnt = (int*)base;            base += (size_t)N_NODES * 4;
    int* batch32 = (int*)base;        base += (size_t)N_NODES * 4;
    ushort_t* wp = (ushort_t*)base;   base += 4 * 16384 * 2;
    float* params = (float*)base;     base += 772 * 4;
    float* gsum = (float*)base;       base += (size_t)NUM_GRAPHS * DIM * 4;    // 256 KB
    int* flags = (int*)base;          base += 16;

    ushort_t* wpA1 = wp;
    ushort_t* wpB1 = wp + 16384;
    ushort_t* wpA2 = wp + 2 * 16384;
    ushort_t* wpB2 = wp + 3 * 16384;

    // Zero degree+gsum, detect dtypes; 256 blocks covers 65536 threads
    zero_detect_kernel<<<256, 256, 0, stream>>>(cnt, gsum, x, ei, flags);
    // Merged canonicalization (edges->ELL XCD-bucketed, x-conv, weights, batch, params)
    prep_all_kernel<<<PREP_TOTAL, 256, 0, stream>>>(x, batch, ei, W1a, W1b, W2a, W2b,
                                                    b1a, b1b, b2a, b2b, Wfc, bfc, flags,
                                                    hX, wp, batch32, params, cnt, ell);

    // Layer 1: agg(x)->hA (reads raw input in place when bf16), mlp in-place on hA
    agg_kernel<<<(N_NODES + 15) / 16, 256, 0, stream>>>(hX, x, flags, cnt, ell, hA);
    mlp_kernel<<<(N_NODES + 63) / 64, 256, 0, stream>>>(hA, wpA1, params + 0, wpB1, params + 128, hA);
    // Layer 2: agg(hA)->hX, then MLP+pool fused (no h2 global write)
    agg_kernel<<<(N_NODES + 15) / 16, 256, 0, stream>>>(hA, hA, nullptr, cnt, ell, hX);
    mlp_pool_kernel<<<(N_NODES + 63) / 64, 256, 0, stream>>>(hX, wpA2, params + 256, wpB2, params + 384,
                                                             batch32, gsum);
    // Final FC from pooled sums
    fc_kernel<<<NUM_GRAPHS, 64, 0, stream>>>(gsum, batch32, params, flags, d_out);
}